// Round 15
// baseline (154.771 us; speedup 1.0000x reference)
//
#include <hip/hip_runtime.h>
#include <hip/hip_bf16.h>

typedef _Float16 f16x8  __attribute__((ext_vector_type(8)));
typedef float    f32x16 __attribute__((ext_vector_type(16)));
typedef float    v2f    __attribute__((ext_vector_type(2)));
typedef unsigned u32x4  __attribute__((ext_vector_type(4)));

#define LOG2E 1.442695040888963f

__device__ __forceinline__ unsigned pk16(float a, float b) {
    return __builtin_bit_cast(unsigned, __builtin_amdgcn_cvt_pkrtz(a, b));
}
__device__ __forceinline__ float fexp2(float x) { return __builtin_amdgcn_exp2f(x); }
__device__ __forceinline__ float frcp(float x)  { return __builtin_amdgcn_rcpf(x); }

// r14 kernel unchanged except occupancy unlock:
//   launch_bounds (256,3) -> (256,6): VGPR cap 85 >= 64 actually used (r14
//   counter), so no spill; 6 blocks/CU = 24 waves/CU.
//   grid 1024 -> 2048 so 6 resident blocks/CU stay fed (2 tiles/block).
// r14 showed neither pipe saturated (trans ~65%, VALU 68%, MFMA 11.5%) at
// 3 blocks/CU -> latency-bound; more waves fill the dependency stalls.
__global__ __launch_bounds__(256, 6) void lstm_mfma_kernel(
    const float* __restrict__ mobility,  // [B,7]
    const float* __restrict__ controls,  // [B,5]
    const float* __restrict__ W_cc, const float* __restrict__ b_cc,
    const float* __restrict__ W_ih, const float* __restrict__ W_hh,
    const float* __restrict__ b_ih, const float* __restrict__ b_hh,
    const float* __restrict__ W1,  const float* __restrict__ b1,
    const float* __restrict__ W2,  const float* __restrict__ b2,
    const float* __restrict__ W3,  const float* __restrict__ b3,
    float* __restrict__ out, int Btot)
{
    const int tid  = threadIdx.x;
    const int lane = tid & 63;
    const int wib  = tid >> 6;
    const int col  = lane & 31;
    const int hi   = lane >> 5;

    const float S2 = 2.0f * LOG2E;

    // ---- LSTM weight fragments (exp2-prescaled), once per block ----
    f16x8 afrag[2], afrag2[2];
    #pragma unroll
    for (int gb = 0; gb < 2; ++gb) {
        const float s = (gb == 0) ? -LOG2E : ((col < 16) ? S2 : -LOG2E);
        const float* wr = W_hh + (gb * 32 + col) * 16 + hi * 8;
        u32x4 aw = { pk16(s * wr[0], s * wr[1]), pk16(s * wr[2], s * wr[3]),
                     pk16(s * wr[4], s * wr[5]), pk16(s * wr[6], s * wr[7]) };
        afrag[gb] = __builtin_bit_cast(f16x8, aw);
        u32x4 a2 = { 0u, 0u, 0u, 0u };
        if (hi == 0) {
            const int gu = gb * 32 + col;
            a2[0] = pk16(s * W_ih[gu], s * (b_ih[gu] + b_hh[gu]));  // k=0: W_ih, k=1: bias
        }
        afrag2[gb] = __builtin_bit_cast(f16x8, a2);
    }

    // ---- fc fragments (rows x 2log2e); control head + b1 fused into a_fc1c ----
    f16x8 a_fc1, a_fc1c, a_fc2;
    {
        u32x4 w1 = {0u,0u,0u,0u}, w1c = {0u,0u,0u,0u}, w2 = {0u,0u,0u,0u};
        if (col < 16) {
            const float* r1 = W1 + col * 19 + hi * 8;     // k = hi*8+e in [0,16)
            w1 = { pk16(S2*r1[0], S2*r1[1]), pk16(S2*r1[2], S2*r1[3]),
                   pk16(S2*r1[4], S2*r1[5]), pk16(S2*r1[6], S2*r1[7]) };
            const float* r2 = W2 + col * 16 + hi * 8;
            w2 = { pk16(S2*r2[0], S2*r2[1]), pk16(S2*r2[2], S2*r2[3]),
                   pk16(S2*r2[4], S2*r2[5]), pk16(S2*r2[6], S2*r2[7]) };
            if (hi == 0) {
                const float wa = W1[col*19+16], wb = W1[col*19+17], wc = W1[col*19+18];
                float cc[5];
                #pragma unroll
                for (int k = 0; k < 5; ++k)
                    cc[k] = wa * W_cc[0*5+k] + wb * W_cc[1*5+k] + wc * W_cc[2*5+k];
                const float bp = b1[col] + wa * b_cc[0] + wb * b_cc[1] + wc * b_cc[2];
                w1c = { pk16(S2*cc[0], S2*cc[1]), pk16(S2*cc[2], S2*cc[3]),
                        pk16(S2*cc[4], S2*bp), 0u };      // k=5 slot = b1' (vs bctl 1.0)
            }
        }
        a_fc1  = __builtin_bit_cast(f16x8, w1);
        a_fc1c = __builtin_bit_cast(f16x8, w1c);
        a_fc2  = __builtin_bit_cast(f16x8, w2);
    }
    const float b3v = b3[0];

    f32x16 fzero;
    #pragma unroll
    for (int r = 0; r < 16; ++r) fzero[r] = 0.0f;

    const v2f one   = { 1.0f, 1.0f };
    const v2f twoL  = { S2, S2 };
    const v2f ntwoL = { -S2, -S2 };

    const int tilesTotal = (Btot + 255) >> 8;      // 4096
    for (int tile = blockIdx.x; tile < tilesTotal; tile += gridDim.x) {
        const int blockRow0 = tile * 256;
        const int r_lo = blockRow0 + wib * 64 + col;
        const int r_hi = r_lo + 32;

        float mlo[7], mhi[7];
        #pragma unroll
        for (int t = 0; t < 7; ++t) { mlo[t] = mobility[(size_t)r_lo * 7 + t]; mhi[t] = mobility[(size_t)r_hi * 7 + t]; }

        float c[2][8];
        #pragma unroll
        for (int rb = 0; rb < 2; ++rb)
            #pragma unroll
            for (int u = 0; u < 8; ++u) c[rb][u] = 0.0f;

        u32x4 bz = { 0u, 0u, 0u, 0u };
        f16x8 bfrag[2];
        bfrag[0] = __builtin_bit_cast(f16x8, bz);
        bfrag[1] = __builtin_bit_cast(f16x8, bz);

        #pragma unroll 1   // rolled: keeps live ranges small (r7 lesson)
        for (int t = 0; t < 7; ++t) {
            #pragma unroll
            for (int rb = 0; rb < 2; ++rb) {
                const float xt = rb ? mhi[t] : mlo[t];

                u32x4 b2w = { 0u, 0u, 0u, 0u };
                if (hi == 0) b2w[0] = pk16(xt, 1.0f);          // B2 = [x ; 1]
                const f16x8 bx = __builtin_bit_cast(f16x8, b2w);

                f32x16 acc0 = __builtin_amdgcn_mfma_f32_32x32x16_f16(afrag2[0], bx, fzero, 0, 0, 0);
                f32x16 a0   = __builtin_amdgcn_mfma_f32_32x32x16_f16(afrag[0], bfrag[rb], acc0, 0, 0, 0);
                f32x16 acc1 = __builtin_amdgcn_mfma_f32_32x32x16_f16(afrag2[1], bx, fzero, 0, 0, 0);
                f32x16 a1   = __builtin_amdgcn_mfma_f32_32x32x16_f16(afrag[1], bfrag[rb], acc1, 0, 0, 0);

                // unit-pair update (r12 formulation)
                float h[8];
                #pragma unroll
                for (int u = 0; u < 8; u += 2) {
                    v2f ea = { fexp2(a0[u]),     fexp2(a0[u + 1]) };   // e^{-gi}
                    v2f ef = { fexp2(a0[u + 8]), fexp2(a0[u + 9]) };   // e^{-gf}
                    v2f eb = { fexp2(a1[u]),     fexp2(a1[u + 1]) };   // e^{2gg}
                    v2f eo = { fexp2(a1[u + 8]), fexp2(a1[u + 9]) };   // e^{-go}
                    v2f pf  = one + ef;
                    v2f pa  = one + ea;
                    v2f den = __builtin_elementwise_fma(pa, eb, pa);   // (1+ea)(eb+1)
                    v2f D   = den * pf;
                    v2f num = __builtin_elementwise_fma(eb, twoL, ntwoL);
                    v2f cv  = { c[rb][u], c[rb][u + 1] };
                    v2f cn  = __builtin_elementwise_fma(cv, den, num * pf);
                    const float rC = frcp(D[0] * D[1]);
                    v2f Dsw = { D[1], D[0] };
                    v2f rCv = { rC, rC };
                    v2f cs  = (cn * Dsw) * rCv;
                    c[rb][u]     = cs[0];
                    c[rb][u + 1] = cs[1];
                    v2f ec = { fexp2(cs[0]), fexp2(cs[1]) };           // e^{2c}
                    v2f ph = one + eo;
                    v2f dh = __builtin_elementwise_fma(ph, ec, ph);    // (1+eo)(ec+1)
                    v2f nh = ec - one;
                    const float rP = frcp(dh[0] * dh[1]);
                    v2f dsw = { dh[1], dh[0] };
                    v2f rPv = { rP, rP };
                    v2f hv  = (nh * dsw) * rPv;
                    h[u]     = hv[0];
                    h[u + 1] = hv[1];
                }
                unsigned q0 = pk16(h[0], h[1]);
                unsigned q1 = pk16(h[2], h[3]);
                unsigned q2 = pk16(h[4], h[5]);
                unsigned q3 = pk16(h[6], h[7]);
                auto s02 = __builtin_amdgcn_permlane32_swap(q0, q2, false, false);
                auto s13 = __builtin_amdgcn_permlane32_swap(q1, q3, false, false);
                u32x4 bw = { s02[0], s13[0], s02[1], s13[1] };
                bfrag[rb] = __builtin_bit_cast(f16x8, bw);
            }
        }

        // ---- fc stage, fully in-wave (no LDS): per-lane b2/W3 gathers ----
        float b2L[8], w3v[8];
        #pragma unroll
        for (int e = 0; e < 8; ++e) {
            const int m = (e & 3) + 8 * (e >> 2) + 4 * hi;    // D-layout row
            b2L[e] = S2 * b2[m];
            w3v[e] = W3[m];
        }

        #pragma unroll
        for (int rb = 0; rb < 2; ++rb) {
            const int grow = rb ? r_hi : r_lo;
            const float* ctl = controls + (size_t)grow * 5;

            u32x4 bcw = { 0u, 0u, 0u, 0u };
            if (hi == 0) {
                bcw[0] = pk16(ctl[0], ctl[1]);
                bcw[1] = pk16(ctl[2], ctl[3]);
                bcw[2] = pk16(ctl[4], 1.0f);                  // k=5 hits b1' slot
            }
            const f16x8 bc = __builtin_bit_cast(f16x8, bcw);

            f32x16 acc = __builtin_amdgcn_mfma_f32_32x32x16_f16(a_fc1c, bc, fzero, 0, 0, 0);
            acc = __builtin_amdgcn_mfma_f32_32x32x16_f16(a_fc1, bfrag[rb], acc, 0, 0, 0);

            // tanh on the 8 valid rows (acc already 2log2e-scaled), pair-merged rcp
            float t1[8];
            #pragma unroll
            for (int r = 0; r < 8; r += 2) {
                const float d0 = fexp2(acc[r])     + 1.0f;
                const float d1 = fexp2(acc[r + 1]) + 1.0f;
                const float rP = frcp(d0 * d1);
                t1[r]     = fmaf(-2.0f * d1, rP, 1.0f);
                t1[r + 1] = fmaf(-2.0f * d0, rP, 1.0f);
            }
            // D->B repack (identical unit mapping as LSTM h)
            unsigned q0 = pk16(t1[0], t1[1]);
            unsigned q1 = pk16(t1[2], t1[3]);
            unsigned q2 = pk16(t1[4], t1[5]);
            unsigned q3 = pk16(t1[6], t1[7]);
            auto s02 = __builtin_amdgcn_permlane32_swap(q0, q2, false, false);
            auto s13 = __builtin_amdgcn_permlane32_swap(q1, q3, false, false);
            u32x4 bw = { s02[0], s13[0], s02[1], s13[1] };
            const f16x8 bt1 = __builtin_bit_cast(f16x8, bw);

            f32x16 acc2 = __builtin_amdgcn_mfma_f32_32x32x16_f16(a_fc2, bt1, fzero, 0, 0, 0);

            float t2[8];
            #pragma unroll
            for (int r = 0; r < 8; r += 2) {
                const float d0 = fexp2(acc2[r]     + b2L[r])     + 1.0f;
                const float d1 = fexp2(acc2[r + 1] + b2L[r + 1]) + 1.0f;
                const float rP = frcp(d0 * d1);
                t2[r]     = fmaf(-2.0f * d1, rP, 1.0f);
                t2[r + 1] = fmaf(-2.0f * d0, rP, 1.0f);
            }

            float dot = t2[0] * w3v[0];
            #pragma unroll
            for (int e = 1; e < 8; ++e) dot = fmaf(t2[e], w3v[e], dot);
            const float tot = dot + __shfl_xor(dot, 32);      // pair-half sum
            const float res = fmaxf(tot + b3v, 0.0f);
            if (hi == 0 && grow < Btot) out[grow] = res;
        }
    }
}

extern "C" void kernel_launch(void* const* d_in, const int* in_sizes, int n_in,
                              void* d_out, int out_size, void* d_ws, size_t ws_size,
                              hipStream_t stream) {
    const float* mobility = (const float*)d_in[0];
    const float* controls = (const float*)d_in[1];
    // d_in[2] = last : unused by the reference
    const float* W_cc = (const float*)d_in[3];
    const float* b_cc = (const float*)d_in[4];
    const float* W_ih = (const float*)d_in[5];
    const float* W_hh = (const float*)d_in[6];
    const float* b_ih = (const float*)d_in[7];
    const float* b_hh = (const float*)d_in[8];
    const float* W1   = (const float*)d_in[9];
    const float* b1   = (const float*)d_in[10];
    const float* W2   = (const float*)d_in[11];
    const float* b2   = (const float*)d_in[12];
    const float* W3   = (const float*)d_in[13];
    const float* b3   = (const float*)d_in[14];
    float* out = (float*)d_out;

    const int Btot  = in_sizes[0] / 7;              // 1048576
    const int tiles = (Btot + 255) / 256;           // 4096
    const int grid  = tiles < 2048 ? tiles : 2048;  // 2 tiles/block; feeds 6 blocks/CU

    lstm_mfma_kernel<<<grid, 256, 0, stream>>>(
        mobility, controls, W_cc, b_cc, W_ih, W_hh, b_ih, b_hh,
        W1, b1, W2, b2, W3, b3, out, Btot);
}

// Round 16
// 100.120 us; speedup vs baseline: 1.5458x; 1.5458x over previous
//
#include <hip/hip_runtime.h>
#include <hip/hip_bf16.h>

typedef _Float16 f16x8  __attribute__((ext_vector_type(8)));
typedef float    f32x16 __attribute__((ext_vector_type(16)));
typedef float    v2f    __attribute__((ext_vector_type(2)));
typedef unsigned u32x4  __attribute__((ext_vector_type(4)));

#define LOG2E 1.442695040888963f

__device__ __forceinline__ unsigned pk16(float a, float b) {
    return __builtin_bit_cast(unsigned, __builtin_amdgcn_cvt_pkrtz(a, b));
}
__device__ __forceinline__ float fexp2(float x) { return __builtin_amdgcn_exp2f(x); }
__device__ __forceinline__ float frcp(float x)  { return __builtin_amdgcn_rcpf(x); }

// r14 kernel, launch_bounds (256,3) -> (256,4): cap 128 = measured total usage
// (64 arch-VGPR + ~64 acc regs; r15's (256,6) cap 85 split 40/45 and spilled
// 112 MB of scratch). 4 waves/EU vs r14's 3; kernel body unchanged.
__global__ __launch_bounds__(256, 4) void lstm_mfma_kernel(
    const float* __restrict__ mobility,  // [B,7]
    const float* __restrict__ controls,  // [B,5]
    const float* __restrict__ W_cc, const float* __restrict__ b_cc,
    const float* __restrict__ W_ih, const float* __restrict__ W_hh,
    const float* __restrict__ b_ih, const float* __restrict__ b_hh,
    const float* __restrict__ W1,  const float* __restrict__ b1,
    const float* __restrict__ W2,  const float* __restrict__ b2,
    const float* __restrict__ W3,  const float* __restrict__ b3,
    float* __restrict__ out, int Btot)
{
    const int tid  = threadIdx.x;
    const int lane = tid & 63;
    const int wib  = tid >> 6;
    const int col  = lane & 31;
    const int hi   = lane >> 5;

    const float S2 = 2.0f * LOG2E;

    // ---- LSTM weight fragments (exp2-prescaled), once per block ----
    f16x8 afrag[2], afrag2[2];
    #pragma unroll
    for (int gb = 0; gb < 2; ++gb) {
        const float s = (gb == 0) ? -LOG2E : ((col < 16) ? S2 : -LOG2E);
        const float* wr = W_hh + (gb * 32 + col) * 16 + hi * 8;
        u32x4 aw = { pk16(s * wr[0], s * wr[1]), pk16(s * wr[2], s * wr[3]),
                     pk16(s * wr[4], s * wr[5]), pk16(s * wr[6], s * wr[7]) };
        afrag[gb] = __builtin_bit_cast(f16x8, aw);
        u32x4 a2 = { 0u, 0u, 0u, 0u };
        if (hi == 0) {
            const int gu = gb * 32 + col;
            a2[0] = pk16(s * W_ih[gu], s * (b_ih[gu] + b_hh[gu]));  // k=0: W_ih, k=1: bias
        }
        afrag2[gb] = __builtin_bit_cast(f16x8, a2);
    }

    // ---- fc fragments (rows x 2log2e); control head + b1 fused into a_fc1c ----
    f16x8 a_fc1, a_fc1c, a_fc2;
    {
        u32x4 w1 = {0u,0u,0u,0u}, w1c = {0u,0u,0u,0u}, w2 = {0u,0u,0u,0u};
        if (col < 16) {
            const float* r1 = W1 + col * 19 + hi * 8;     // k = hi*8+e in [0,16)
            w1 = { pk16(S2*r1[0], S2*r1[1]), pk16(S2*r1[2], S2*r1[3]),
                   pk16(S2*r1[4], S2*r1[5]), pk16(S2*r1[6], S2*r1[7]) };
            const float* r2 = W2 + col * 16 + hi * 8;
            w2 = { pk16(S2*r2[0], S2*r2[1]), pk16(S2*r2[2], S2*r2[3]),
                   pk16(S2*r2[4], S2*r2[5]), pk16(S2*r2[6], S2*r2[7]) };
            if (hi == 0) {
                const float wa = W1[col*19+16], wb = W1[col*19+17], wc = W1[col*19+18];
                float cc[5];
                #pragma unroll
                for (int k = 0; k < 5; ++k)
                    cc[k] = wa * W_cc[0*5+k] + wb * W_cc[1*5+k] + wc * W_cc[2*5+k];
                const float bp = b1[col] + wa * b_cc[0] + wb * b_cc[1] + wc * b_cc[2];
                w1c = { pk16(S2*cc[0], S2*cc[1]), pk16(S2*cc[2], S2*cc[3]),
                        pk16(S2*cc[4], S2*bp), 0u };      // k=5 slot = b1' (vs bctl 1.0)
            }
        }
        a_fc1  = __builtin_bit_cast(f16x8, w1);
        a_fc1c = __builtin_bit_cast(f16x8, w1c);
        a_fc2  = __builtin_bit_cast(f16x8, w2);
    }
    const float b3v = b3[0];

    f32x16 fzero;
    #pragma unroll
    for (int r = 0; r < 16; ++r) fzero[r] = 0.0f;

    const v2f one   = { 1.0f, 1.0f };
    const v2f twoL  = { S2, S2 };
    const v2f ntwoL = { -S2, -S2 };

    const int tilesTotal = (Btot + 255) >> 8;      // 4096
    for (int tile = blockIdx.x; tile < tilesTotal; tile += gridDim.x) {
        const int blockRow0 = tile * 256;
        const int r_lo = blockRow0 + wib * 64 + col;
        const int r_hi = r_lo + 32;

        float mlo[7], mhi[7];
        #pragma unroll
        for (int t = 0; t < 7; ++t) { mlo[t] = mobility[(size_t)r_lo * 7 + t]; mhi[t] = mobility[(size_t)r_hi * 7 + t]; }

        float c[2][8];
        #pragma unroll
        for (int rb = 0; rb < 2; ++rb)
            #pragma unroll
            for (int u = 0; u < 8; ++u) c[rb][u] = 0.0f;

        u32x4 bz = { 0u, 0u, 0u, 0u };
        f16x8 bfrag[2];
        bfrag[0] = __builtin_bit_cast(f16x8, bz);
        bfrag[1] = __builtin_bit_cast(f16x8, bz);

        #pragma unroll 1   // rolled: keeps live ranges small (r7 lesson)
        for (int t = 0; t < 7; ++t) {
            #pragma unroll
            for (int rb = 0; rb < 2; ++rb) {
                const float xt = rb ? mhi[t] : mlo[t];

                u32x4 b2w = { 0u, 0u, 0u, 0u };
                if (hi == 0) b2w[0] = pk16(xt, 1.0f);          // B2 = [x ; 1]
                const f16x8 bx = __builtin_bit_cast(f16x8, b2w);

                f32x16 acc0 = __builtin_amdgcn_mfma_f32_32x32x16_f16(afrag2[0], bx, fzero, 0, 0, 0);
                f32x16 a0   = __builtin_amdgcn_mfma_f32_32x32x16_f16(afrag[0], bfrag[rb], acc0, 0, 0, 0);
                f32x16 acc1 = __builtin_amdgcn_mfma_f32_32x32x16_f16(afrag2[1], bx, fzero, 0, 0, 0);
                f32x16 a1   = __builtin_amdgcn_mfma_f32_32x32x16_f16(afrag[1], bfrag[rb], acc1, 0, 0, 0);

                // unit-pair update (r12 formulation)
                float h[8];
                #pragma unroll
                for (int u = 0; u < 8; u += 2) {
                    v2f ea = { fexp2(a0[u]),     fexp2(a0[u + 1]) };   // e^{-gi}
                    v2f ef = { fexp2(a0[u + 8]), fexp2(a0[u + 9]) };   // e^{-gf}
                    v2f eb = { fexp2(a1[u]),     fexp2(a1[u + 1]) };   // e^{2gg}
                    v2f eo = { fexp2(a1[u + 8]), fexp2(a1[u + 9]) };   // e^{-go}
                    v2f pf  = one + ef;
                    v2f pa  = one + ea;
                    v2f den = __builtin_elementwise_fma(pa, eb, pa);   // (1+ea)(eb+1)
                    v2f D   = den * pf;
                    v2f num = __builtin_elementwise_fma(eb, twoL, ntwoL);
                    v2f cv  = { c[rb][u], c[rb][u + 1] };
                    v2f cn  = __builtin_elementwise_fma(cv, den, num * pf);
                    const float rC = frcp(D[0] * D[1]);
                    v2f Dsw = { D[1], D[0] };
                    v2f rCv = { rC, rC };
                    v2f cs  = (cn * Dsw) * rCv;
                    c[rb][u]     = cs[0];
                    c[rb][u + 1] = cs[1];
                    v2f ec = { fexp2(cs[0]), fexp2(cs[1]) };           // e^{2c}
                    v2f ph = one + eo;
                    v2f dh = __builtin_elementwise_fma(ph, ec, ph);    // (1+eo)(ec+1)
                    v2f nh = ec - one;
                    const float rP = frcp(dh[0] * dh[1]);
                    v2f dsw = { dh[1], dh[0] };
                    v2f rPv = { rP, rP };
                    v2f hv  = (nh * dsw) * rPv;
                    h[u]     = hv[0];
                    h[u + 1] = hv[1];
                }
                unsigned q0 = pk16(h[0], h[1]);
                unsigned q1 = pk16(h[2], h[3]);
                unsigned q2 = pk16(h[4], h[5]);
                unsigned q3 = pk16(h[6], h[7]);
                auto s02 = __builtin_amdgcn_permlane32_swap(q0, q2, false, false);
                auto s13 = __builtin_amdgcn_permlane32_swap(q1, q3, false, false);
                u32x4 bw = { s02[0], s13[0], s02[1], s13[1] };
                bfrag[rb] = __builtin_bit_cast(f16x8, bw);
            }
        }

        // ---- fc stage, fully in-wave (no LDS): per-lane b2/W3 gathers ----
        float b2L[8], w3v[8];
        #pragma unroll
        for (int e = 0; e < 8; ++e) {
            const int m = (e & 3) + 8 * (e >> 2) + 4 * hi;    // D-layout row
            b2L[e] = S2 * b2[m];
            w3v[e] = W3[m];
        }

        #pragma unroll
        for (int rb = 0; rb < 2; ++rb) {
            const int grow = rb ? r_hi : r_lo;
            const float* ctl = controls + (size_t)grow * 5;

            u32x4 bcw = { 0u, 0u, 0u, 0u };
            if (hi == 0) {
                bcw[0] = pk16(ctl[0], ctl[1]);
                bcw[1] = pk16(ctl[2], ctl[3]);
                bcw[2] = pk16(ctl[4], 1.0f);                  // k=5 hits b1' slot
            }
            const f16x8 bc = __builtin_bit_cast(f16x8, bcw);

            f32x16 acc = __builtin_amdgcn_mfma_f32_32x32x16_f16(a_fc1c, bc, fzero, 0, 0, 0);
            acc = __builtin_amdgcn_mfma_f32_32x32x16_f16(a_fc1, bfrag[rb], acc, 0, 0, 0);

            // tanh on the 8 valid rows (acc already 2log2e-scaled), pair-merged rcp
            float t1[8];
            #pragma unroll
            for (int r = 0; r < 8; r += 2) {
                const float d0 = fexp2(acc[r])     + 1.0f;
                const float d1 = fexp2(acc[r + 1]) + 1.0f;
                const float rP = frcp(d0 * d1);
                t1[r]     = fmaf(-2.0f * d1, rP, 1.0f);
                t1[r + 1] = fmaf(-2.0f * d0, rP, 1.0f);
            }
            // D->B repack (identical unit mapping as LSTM h)
            unsigned q0 = pk16(t1[0], t1[1]);
            unsigned q1 = pk16(t1[2], t1[3]);
            unsigned q2 = pk16(t1[4], t1[5]);
            unsigned q3 = pk16(t1[6], t1[7]);
            auto s02 = __builtin_amdgcn_permlane32_swap(q0, q2, false, false);
            auto s13 = __builtin_amdgcn_permlane32_swap(q1, q3, false, false);
            u32x4 bw = { s02[0], s13[0], s02[1], s13[1] };
            const f16x8 bt1 = __builtin_bit_cast(f16x8, bw);

            f32x16 acc2 = __builtin_amdgcn_mfma_f32_32x32x16_f16(a_fc2, bt1, fzero, 0, 0, 0);

            float t2[8];
            #pragma unroll
            for (int r = 0; r < 8; r += 2) {
                const float d0 = fexp2(acc2[r]     + b2L[r])     + 1.0f;
                const float d1 = fexp2(acc2[r + 1] + b2L[r + 1]) + 1.0f;
                const float rP = frcp(d0 * d1);
                t2[r]     = fmaf(-2.0f * d1, rP, 1.0f);
                t2[r + 1] = fmaf(-2.0f * d0, rP, 1.0f);
            }

            float dot = t2[0] * w3v[0];
            #pragma unroll
            for (int e = 1; e < 8; ++e) dot = fmaf(t2[e], w3v[e], dot);
            const float tot = dot + __shfl_xor(dot, 32);      // pair-half sum
            const float res = fmaxf(tot + b3v, 0.0f);
            if (hi == 0 && grow < Btot) out[grow] = res;
        }
    }
}

extern "C" void kernel_launch(void* const* d_in, const int* in_sizes, int n_in,
                              void* d_out, int out_size, void* d_ws, size_t ws_size,
                              hipStream_t stream) {
    const float* mobility = (const float*)d_in[0];
    const float* controls = (const float*)d_in[1];
    // d_in[2] = last : unused by the reference
    const float* W_cc = (const float*)d_in[3];
    const float* b_cc = (const float*)d_in[4];
    const float* W_ih = (const float*)d_in[5];
    const float* W_hh = (const float*)d_in[6];
    const float* b_ih = (const float*)d_in[7];
    const float* b_hh = (const float*)d_in[8];
    const float* W1   = (const float*)d_in[9];
    const float* b1   = (const float*)d_in[10];
    const float* W2   = (const float*)d_in[11];
    const float* b2   = (const float*)d_in[12];
    const float* W3   = (const float*)d_in[13];
    const float* b3   = (const float*)d_in[14];
    float* out = (float*)d_out;

    const int Btot  = in_sizes[0] / 7;              // 1048576
    const int tiles = (Btot + 255) / 256;           // 4096
    const int grid  = tiles < 2048 ? tiles : 2048;  // 2 tiles/block

    lstm_mfma_kernel<<<grid, 256, 0, stream>>>(
        mobility, controls, W_cc, b_cc, W_ih, W_hh, b_ih, b_hh,
        W1, b1, W2, b2, W3, b3, out, Btot);
}